// Round 1
// baseline (604.364 us; speedup 1.0000x reference)
//
#include <hip/hip_runtime.h>

#define IN_DIM 128
#define HIDV 128
#define NHEADS 4

typedef unsigned int u32;
typedef unsigned short u16;

__device__ __forceinline__ float bf2f(u32 bits16) { return __uint_as_float(bits16 << 16); }
__device__ __forceinline__ u16 f2bf(float f) {
  u32 u = __float_as_uint(f);
  u += 0x7fffu + ((u >> 16) & 1u);
  return (u16)(u >> 16);
}

// ---------------- edge preprocessing ----------------

// Detect whether edge_index is int64 or int32: for int64 (values < 2^31),
// every odd 32-bit word is 0. For int32 random indices that is impossible.
__global__ void k_detect(const u32* __restrict__ ei, int* __restrict__ eflag, int E) {
  if (threadIdx.x == 0 && blockIdx.x == 0) {
    int i64 = 1;
    int kmax = (2 * E < 257) ? 2 * E : 257;
    for (int k = 1; k < kmax; k += 2) i64 &= (ei[k] == 0u);
    *eflag = i64;
  }
}

__global__ void k_convert(const void* __restrict__ ei, int* __restrict__ src32,
                          int* __restrict__ dst32, int E, const int* __restrict__ eflag) {
  int i = blockIdx.x * blockDim.x + threadIdx.x;
  if (i >= E) return;
  if (*eflag) {
    const long long* p = (const long long*)ei;
    src32[i] = (int)p[i];
    dst32[i] = (int)p[E + i];
  } else {
    const int* p = (const int*)ei;
    src32[i] = p[i];
    dst32[i] = p[E + i];
  }
}

__global__ void k_count(const int* __restrict__ dst32, int* __restrict__ cnt, int E) {
  int i = blockIdx.x * blockDim.x + threadIdx.x;
  if (i < E) atomicAdd(&cnt[dst32[i]], 1);
}

// Allocate CSR row offsets: one atomic per wave via wave-level inclusive scan.
__global__ void k_alloc(const int* __restrict__ cnt, int* __restrict__ rowp,
                        int* __restrict__ cursor, int* __restrict__ total, int N) {
  int i = blockIdx.x * blockDim.x + threadIdx.x;
  int lane = threadIdx.x & 63;
  int v = (i < N) ? cnt[i] + 1 : 0;  // +1: self loop
  int s = v;
  #pragma unroll
  for (int off = 1; off < 64; off <<= 1) {
    int t = __shfl_up(s, off);
    if (lane >= off) s += t;
  }
  int waveTotal = __shfl(s, 63);
  int base = 0;
  if (lane == 63) base = atomicAdd(total, waveTotal);
  base = __shfl(base, 63);
  int r = base + s - v;  // exclusive
  if (i < N) { rowp[i] = r; cursor[i] = r; }
}

__global__ void k_scatter(const int* __restrict__ src32, const int* __restrict__ dst32,
                          int* __restrict__ cursor, int* __restrict__ csr, int E, int N) {
  int i = blockIdx.x * blockDim.x + threadIdx.x;
  if (i < E) {
    int p = atomicAdd(&cursor[dst32[i]], 1);
    csr[p] = src32[i];
  } else if (i < E + N) {
    int n = i - E;
    int p = atomicAdd(&cursor[n], 1);
    csr[p] = n;  // self loop
  }
}

// ---------------- GEMM (fp32 compute, templated A/C dtype) ----------------

__device__ __forceinline__ void load4f(const float* p, float* d) {
  const float4 v = *reinterpret_cast<const float4*>(p);
  d[0] = v.x; d[1] = v.y; d[2] = v.z; d[3] = v.w;
}
__device__ __forceinline__ void load4f(const u16* p, float* d) {
  const ushort4 v = *reinterpret_cast<const ushort4*>(p);
  d[0] = bf2f(v.x); d[1] = bf2f(v.y); d[2] = bf2f(v.z); d[3] = bf2f(v.w);
}
__device__ __forceinline__ void store4f(float* p, const float* a) {
  float4 v; v.x = a[0]; v.y = a[1]; v.z = a[2]; v.w = a[3];
  *reinterpret_cast<float4*>(p) = v;
}
__device__ __forceinline__ void store4f(u16* p, const float* a) {
  ushort4 v; v.x = f2bf(a[0]); v.y = f2bf(a[1]); v.z = f2bf(a[2]); v.w = f2bf(a[3]);
  *reinterpret_cast<ushort4*>(p) = v;
}

template<typename AT, typename CT>
__global__ __launch_bounds__(256) void k_gemm(const AT* __restrict__ A, const float* __restrict__ B,
                                              CT* __restrict__ C, int M, int N, int K) {
  __shared__ float As[16][65];
  __shared__ float Bs[16][64];
  const int tid = threadIdx.x;
  const int m0 = blockIdx.x * 64;
  const int n0 = blockIdx.y * 64;
  const int tx = tid & 15, ty = tid >> 4;
  const int arow = tid >> 2, acol = (tid & 3) * 4;
  const int brow = tid >> 4, bcol = (tid & 15) * 4;
  float acc[4][4] = {};
  for (int k0 = 0; k0 < K; k0 += 16) {
    float av[4] = {0.f, 0.f, 0.f, 0.f};
    int gm = m0 + arow;
    if (gm < M) load4f(A + (size_t)gm * K + k0 + acol, av);
    As[acol + 0][arow] = av[0];
    As[acol + 1][arow] = av[1];
    As[acol + 2][arow] = av[2];
    As[acol + 3][arow] = av[3];
    float bv[4];
    load4f(B + (size_t)(k0 + brow) * N + n0 + bcol, bv);
    float4 b4; b4.x = bv[0]; b4.y = bv[1]; b4.z = bv[2]; b4.w = bv[3];
    *reinterpret_cast<float4*>(&Bs[brow][bcol]) = b4;
    __syncthreads();
    #pragma unroll
    for (int k = 0; k < 16; ++k) {
      float a[4], b[4];
      #pragma unroll
      for (int i = 0; i < 4; ++i) a[i] = As[k][ty * 4 + i];
      #pragma unroll
      for (int j = 0; j < 4; ++j) b[j] = Bs[k][tx * 4 + j];
      #pragma unroll
      for (int i = 0; i < 4; ++i)
        #pragma unroll
        for (int j = 0; j < 4; ++j)
          acc[i][j] = fmaf(a[i], b[j], acc[i][j]);
    }
    __syncthreads();
  }
  #pragma unroll
  for (int i = 0; i < 4; ++i) {
    int gm = m0 + ty * 4 + i;
    if (gm < M) store4f(&C[(size_t)gm * N + n0 + tx * 4], acc[i]);
  }
}

// ---------------- attention coefficient kernels ----------------

// xh1 bf16 [N,512]; compute alpha_s/alpha_d [N,4]. One wave per node.
__global__ __launch_bounds__(256) void k_alpha1(const u16* __restrict__ xh,
                                                const float* __restrict__ a_src,
                                                const float* __restrict__ a_dst,
                                                float* __restrict__ as_out,
                                                float* __restrict__ ad_out, int N) {
  int g = blockIdx.x * 4 + (threadIdx.x >> 6);
  int lane = threadIdx.x & 63;
  if (g >= N) return;
  const u32* urow = (const u32*)(xh + (size_t)g * 512);
  float sv[4], dv[4];
  #pragma unroll
  for (int h = 0; h < 4; ++h) {
    u32 w = urow[h * 64 + lane];
    float x0 = bf2f(w & 0xffffu), x1 = bf2f(w >> 16);
    int c = h * 128 + 2 * lane;
    sv[h] = x0 * a_src[c] + x1 * a_src[c + 1];
    dv[h] = x0 * a_dst[c] + x1 * a_dst[c + 1];
  }
  #pragma unroll
  for (int s = 32; s; s >>= 1) {
    #pragma unroll
    for (int h = 0; h < 4; ++h) {
      sv[h] += __shfl_xor(sv[h], s);
      dv[h] += __shfl_xor(dv[h], s);
    }
  }
  if (lane == 0) {
    #pragma unroll
    for (int h = 0; h < 4; ++h) {
      as_out[g * 4 + h] = sv[h];
      ad_out[g * 4 + h] = dv[h];
    }
  }
}

// xh2 f32 [N,128]; alpha_s/alpha_d [N]. One wave per node.
__global__ __launch_bounds__(256) void k_alpha2(const float* __restrict__ xh,
                                                const float* __restrict__ a_src,
                                                const float* __restrict__ a_dst,
                                                float* __restrict__ as_out,
                                                float* __restrict__ ad_out, int N) {
  int g = blockIdx.x * 4 + (threadIdx.x >> 6);
  int lane = threadIdx.x & 63;
  if (g >= N) return;
  const float* r = xh + (size_t)g * 128;
  float vs = r[lane] * a_src[lane] + r[64 + lane] * a_src[64 + lane];
  float vd = r[lane] * a_dst[lane] + r[64 + lane] * a_dst[64 + lane];
  #pragma unroll
  for (int s = 32; s; s >>= 1) {
    vs += __shfl_xor(vs, s);
    vd += __shfl_xor(vd, s);
  }
  if (lane == 0) { as_out[g] = vs; ad_out[g] = vd; }
}

// ---------------- GAT aggregation ----------------

#define EXCAP1 512
__global__ __launch_bounds__(256) void k_agg1(
    const u16* __restrict__ xh, const float* __restrict__ as_, const float* __restrict__ ad_,
    const int* __restrict__ csr, const int* __restrict__ rowp, const int* __restrict__ cnt,
    const float* __restrict__ bias, u16* __restrict__ hout, int N) {
  __shared__ float s_ex[EXCAP1][4];
  __shared__ int s_src[EXCAP1];
  __shared__ float s_red[16];
  const int dn = blockIdx.x;
  if (dn >= N) return;
  const int tid = threadIdx.x;
  const int lane = tid & 63, wv = tid >> 6;
  const int start = rowp[dn];
  const int deg = cnt[dn] + 1;
  const float ad0 = ad_[dn * 4 + 0], ad1 = ad_[dn * 4 + 1];
  const float ad2 = ad_[dn * 4 + 2], ad3 = ad_[dn * 4 + 3];
  float m0 = -1e30f, m1 = -1e30f, m2 = -1e30f, m3 = -1e30f;
  for (int i = tid; i < deg; i += 256) {
    const float* ap = as_ + (size_t)csr[start + i] * 4;
    float e;
    e = ap[0] + ad0; e = e > 0.f ? e : 0.2f * e; m0 = fmaxf(m0, e);
    e = ap[1] + ad1; e = e > 0.f ? e : 0.2f * e; m1 = fmaxf(m1, e);
    e = ap[2] + ad2; e = e > 0.f ? e : 0.2f * e; m2 = fmaxf(m2, e);
    e = ap[3] + ad3; e = e > 0.f ? e : 0.2f * e; m3 = fmaxf(m3, e);
  }
  #pragma unroll
  for (int s = 32; s; s >>= 1) {
    m0 = fmaxf(m0, __shfl_xor(m0, s));
    m1 = fmaxf(m1, __shfl_xor(m1, s));
    m2 = fmaxf(m2, __shfl_xor(m2, s));
    m3 = fmaxf(m3, __shfl_xor(m3, s));
  }
  if (lane == 0) {
    s_red[wv * 4 + 0] = m0; s_red[wv * 4 + 1] = m1;
    s_red[wv * 4 + 2] = m2; s_red[wv * 4 + 3] = m3;
  }
  __syncthreads();
  m0 = fmaxf(fmaxf(s_red[0], s_red[4]), fmaxf(s_red[8], s_red[12]));
  m1 = fmaxf(fmaxf(s_red[1], s_red[5]), fmaxf(s_red[9], s_red[13]));
  m2 = fmaxf(fmaxf(s_red[2], s_red[6]), fmaxf(s_red[10], s_red[14]));
  m3 = fmaxf(fmaxf(s_red[3], s_red[7]), fmaxf(s_red[11], s_red[15]));

  float d0 = 0.f, d1 = 0.f, d2 = 0.f, d3 = 0.f;
  float acc0 = 0.f, acc1 = 0.f;
  const int hj = tid >> 6;  // head owned by this thread's channel pair
  for (int c0 = 0; c0 < deg; c0 += EXCAP1) {
    const int cn = min(EXCAP1, deg - c0);
    __syncthreads();
    for (int i = tid; i < cn; i += 256) {
      int s = csr[start + c0 + i];
      s_src[i] = s;
      const float* ap = as_ + (size_t)s * 4;
      float e, ex;
      e = ap[0] + ad0; e = e > 0.f ? e : 0.2f * e; ex = __expf(e - m0); s_ex[i][0] = ex; d0 += ex;
      e = ap[1] + ad1; e = e > 0.f ? e : 0.2f * e; ex = __expf(e - m1); s_ex[i][1] = ex; d1 += ex;
      e = ap[2] + ad2; e = e > 0.f ? e : 0.2f * e; ex = __expf(e - m2); s_ex[i][2] = ex; d2 += ex;
      e = ap[3] + ad3; e = e > 0.f ? e : 0.2f * e; ex = __expf(e - m3); s_ex[i][3] = ex; d3 += ex;
    }
    __syncthreads();
    for (int i = 0; i < cn; ++i) {
      const u32 wrd = *(const u32*)(xh + (size_t)s_src[i] * 512 + tid * 2);
      const float ex = s_ex[i][hj];
      acc0 = fmaf(ex, bf2f(wrd & 0xffffu), acc0);
      acc1 = fmaf(ex, bf2f(wrd >> 16), acc1);
    }
  }
  #pragma unroll
  for (int s = 32; s; s >>= 1) {
    d0 += __shfl_xor(d0, s); d1 += __shfl_xor(d1, s);
    d2 += __shfl_xor(d2, s); d3 += __shfl_xor(d3, s);
  }
  __syncthreads();
  if (lane == 0) {
    s_red[wv * 4 + 0] = d0; s_red[wv * 4 + 1] = d1;
    s_red[wv * 4 + 2] = d2; s_red[wv * 4 + 3] = d3;
  }
  __syncthreads();
  const float denom = s_red[hj] + s_red[4 + hj] + s_red[8 + hj] + s_red[12 + hj];
  const int j0 = tid * 2;
  float v0 = acc0 / denom + bias[j0];
  float v1 = acc1 / denom + bias[j0 + 1];
  v0 = v0 > 0.f ? v0 : __expf(v0) - 1.f;  // ELU fused
  v1 = v1 > 0.f ? v1 : __expf(v1) - 1.f;
  ((u32*)(hout + (size_t)dn * 512))[tid] = (u32)f2bf(v0) | ((u32)f2bf(v1) << 16);
}

#define EXCAP2 1024
__global__ __launch_bounds__(128) void k_agg2(
    const float* __restrict__ xh, const float* __restrict__ as_, const float* __restrict__ ad_,
    const int* __restrict__ csr, const int* __restrict__ rowp, const int* __restrict__ cnt,
    const float* __restrict__ bias, float* __restrict__ hout, int N) {
  __shared__ float s_ex[EXCAP2];
  __shared__ int s_src[EXCAP2];
  __shared__ float s_red[2];
  const int dn = blockIdx.x;
  if (dn >= N) return;
  const int tid = threadIdx.x, lane = tid & 63, wv = tid >> 6;
  const int start = rowp[dn];
  const int deg = cnt[dn] + 1;
  const float adv = ad_[dn];
  float mx = -1e30f;
  for (int i = tid; i < deg; i += 128) {
    float e = as_[csr[start + i]] + adv;
    e = e > 0.f ? e : 0.2f * e;
    mx = fmaxf(mx, e);
  }
  #pragma unroll
  for (int s = 32; s; s >>= 1) mx = fmaxf(mx, __shfl_xor(mx, s));
  if (lane == 0) s_red[wv] = mx;
  __syncthreads();
  mx = fmaxf(s_red[0], s_red[1]);
  float dsum = 0.f, acc = 0.f;
  for (int c0 = 0; c0 < deg; c0 += EXCAP2) {
    int cn = min(EXCAP2, deg - c0);
    __syncthreads();
    for (int i = tid; i < cn; i += 128) {
      int s = csr[start + c0 + i];
      s_src[i] = s;
      float e = as_[s] + adv;
      e = e > 0.f ? e : 0.2f * e;
      float ex = __expf(e - mx);
      s_ex[i] = ex;
      dsum += ex;
    }
    __syncthreads();
    for (int i = 0; i < cn; ++i)
      acc = fmaf(s_ex[i], xh[(size_t)s_src[i] * 128 + tid], acc);
  }
  #pragma unroll
  for (int s = 32; s; s >>= 1) dsum += __shfl_xor(dsum, s);
  __syncthreads();
  if (lane == 0) s_red[wv] = dsum;
  __syncthreads();
  hout[(size_t)dn * 128 + tid] = acc / (s_red[0] + s_red[1]) + bias[tid];
}

// ---------------- final regression head ----------------
__global__ __launch_bounds__(256) void k_head(const float* __restrict__ h2,
                                              const float* __restrict__ fcw,
                                              const float* __restrict__ fcb,
                                              float* __restrict__ out, int N) {
  int g = blockIdx.x * 4 + (threadIdx.x >> 6);
  int lane = threadIdx.x & 63;
  if (g >= N) return;
  const float* r = h2 + (size_t)g * 128;
  float acc = r[lane] * fcw[lane] + r[64 + lane] * fcw[64 + lane];
  #pragma unroll
  for (int s = 32; s; s >>= 1) acc += __shfl_xor(acc, s);
  if (lane == 0) out[g] = acc + fcb[0];
}

// ---------------- launch ----------------
extern "C" void kernel_launch(void* const* d_in, const int* in_sizes, int n_in,
                              void* d_out, int out_size, void* d_ws, size_t ws_size,
                              hipStream_t stream) {
  const float* x      = (const float*)d_in[0];
  const void*  ei     = d_in[1];
  const float* W1     = (const float*)d_in[2];
  const float* a_src1 = (const float*)d_in[3];
  const float* a_dst1 = (const float*)d_in[4];
  const float* b1     = (const float*)d_in[5];
  const float* W2     = (const float*)d_in[6];
  const float* a_src2 = (const float*)d_in[7];
  const float* a_dst2 = (const float*)d_in[8];
  const float* b2     = (const float*)d_in[9];
  const float* fc_w   = (const float*)d_in[10];
  const float* fc_b   = (const float*)d_in[11];
  const int N = in_sizes[0] / IN_DIM;
  const int E = in_sizes[1] / 2;

  char* w = (char*)d_ws;
  size_t off = 0;
  auto take = [&](size_t bytes) -> char* {
    char* p = w + off;
    off += (bytes + 255) & ~(size_t)255;
    return p;
  };
  int*   hdr    = (int*)take(256);                 // [0]=eflag, [1]=total
  int*   src32  = (int*)take((size_t)E * 4);
  int*   dst32  = (int*)take((size_t)E * 4);
  int*   cnt    = (int*)take((size_t)N * 4);
  int*   rowp   = (int*)take((size_t)N * 4);
  int*   cursor = (int*)take((size_t)N * 4);
  int*   csr    = (int*)take((size_t)(E + N) * 4);
  float* as1    = (float*)take((size_t)N * 16);
  float* ad1    = (float*)take((size_t)N * 16);
  float* as2    = (float*)take((size_t)N * 4);
  float* ad2    = (float*)take((size_t)N * 4);
  u16*   xh1    = (u16*)take((size_t)N * 512 * 2);
  u16*   h1     = (u16*)take((size_t)N * 512 * 2);
  float* xh2    = (float*)take((size_t)N * 128 * 4);
  float* h2     = (float*)take((size_t)N * 128 * 4);
  (void)ws_size; (void)n_in; (void)out_size;

  hipMemsetAsync(hdr, 0, 256, stream);
  hipMemsetAsync(cnt, 0, (size_t)N * 4, stream);

  k_detect<<<1, 64, 0, stream>>>((const u32*)ei, hdr, E);
  const int gE = (E + 255) / 256;
  k_convert<<<gE, 256, 0, stream>>>(ei, src32, dst32, E, hdr);
  k_count<<<gE, 256, 0, stream>>>(dst32, cnt, E);
  k_alloc<<<(N + 255) / 256, 256, 0, stream>>>(cnt, rowp, cursor, hdr + 1, N);
  k_scatter<<<(E + N + 255) / 256, 256, 0, stream>>>(src32, dst32, cursor, csr, E, N);

  const int mt = (N + 63) / 64;
  k_gemm<float, u16><<<dim3(mt, 8), 256, 0, stream>>>(x, W1, xh1, N, 512, 128);
  k_alpha1<<<(N + 3) / 4, 256, 0, stream>>>(xh1, a_src1, a_dst1, as1, ad1, N);
  k_agg1<<<N, 256, 0, stream>>>(xh1, as1, ad1, csr, rowp, cnt, b1, h1, N);

  k_gemm<u16, float><<<dim3(mt, 2), 256, 0, stream>>>(h1, W2, xh2, N, 128, 512);
  k_alpha2<<<(N + 3) / 4, 256, 0, stream>>>(xh2, a_src2, a_dst2, as2, ad2, N);
  k_agg2<<<N, 128, 0, stream>>>(xh2, as2, ad2, csr, rowp, cnt, b2, h2, N);

  k_head<<<(N + 3) / 4, 256, 0, stream>>>(h2, fc_w, fc_b, (float*)d_out, N);
}

// Round 2
// 388.993 us; speedup vs baseline: 1.5537x; 1.5537x over previous
//
#include <hip/hip_runtime.h>

#define IN_DIM 128

typedef unsigned int u32;
typedef unsigned short u16;
typedef __attribute__((ext_vector_type(8))) short bf16x8;
typedef __attribute__((ext_vector_type(4))) float f32x4;

__device__ __forceinline__ float bf2f(u32 bits16) { return __uint_as_float(bits16 << 16); }
__device__ __forceinline__ u16 f2bf(float f) {
  u32 u = __float_as_uint(f);
  u += 0x7fffu + ((u >> 16) & 1u);
  return (u16)(u >> 16);
}

// ---------------- edge preprocessing ----------------

__global__ void k_detect(const u32* __restrict__ ei, int* __restrict__ eflag, int E) {
  if (threadIdx.x == 0 && blockIdx.x == 0) {
    int i64 = 1;
    int kmax = (2 * E < 257) ? 2 * E : 257;
    for (int k = 1; k < kmax; k += 2) i64 &= (ei[k] == 0u);
    *eflag = i64;
  }
}

__global__ void k_convert(const void* __restrict__ ei, int* __restrict__ src32,
                          int* __restrict__ dst32, int E, const int* __restrict__ eflag) {
  int i = blockIdx.x * blockDim.x + threadIdx.x;
  if (i >= E) return;
  if (*eflag) {
    const long long* p = (const long long*)ei;
    src32[i] = (int)p[i];
    dst32[i] = (int)p[E + i];
  } else {
    const int* p = (const int*)ei;
    src32[i] = p[i];
    dst32[i] = p[E + i];
  }
}

__global__ void k_count(const int* __restrict__ dst32, int* __restrict__ cnt, int E) {
  int i = blockIdx.x * blockDim.x + threadIdx.x;
  if (i < E) atomicAdd(&cnt[dst32[i]], 1);
}

__global__ void k_alloc(const int* __restrict__ cnt, int* __restrict__ rowp,
                        int* __restrict__ cursor, int* __restrict__ total, int N) {
  int i = blockIdx.x * blockDim.x + threadIdx.x;
  int lane = threadIdx.x & 63;
  int v = (i < N) ? cnt[i] + 1 : 0;  // +1: self loop
  int s = v;
  #pragma unroll
  for (int off = 1; off < 64; off <<= 1) {
    int t = __shfl_up(s, off);
    if (lane >= off) s += t;
  }
  int waveTotal = __shfl(s, 63);
  int base = 0;
  if (lane == 63) base = atomicAdd(total, waveTotal);
  base = __shfl(base, 63);
  int r = base + s - v;  // exclusive
  if (i < N) { rowp[i] = r; cursor[i] = r; }
}

__global__ void k_scatter(const int* __restrict__ src32, const int* __restrict__ dst32,
                          int* __restrict__ cursor, int* __restrict__ csr, int E, int N) {
  int i = blockIdx.x * blockDim.x + threadIdx.x;
  if (i < E) {
    int p = atomicAdd(&cursor[dst32[i]], 1);
    csr[p] = src32[i];
  } else if (i < E + N) {
    int n = i - E;
    int p = atomicAdd(&cursor[n], 1);
    csr[p] = n;  // self loop
  }
}

// ---------------- dtype prep ----------------

__global__ void k_castbf(const float* __restrict__ in, u16* __restrict__ out, int n4) {
  int i = blockIdx.x * blockDim.x + threadIdx.x;
  if (i >= n4) return;
  float4 v = ((const float4*)in)[i];
  ushort4 o;
  o.x = f2bf(v.x); o.y = f2bf(v.y); o.z = f2bf(v.z); o.w = f2bf(v.w);
  ((ushort4*)out)[i] = o;
}

// W [K][NN] fp32 -> WT [NN][K] bf16
__global__ void k_transW(const float* __restrict__ W, u16* __restrict__ WT, int K, int NN) {
  int i = blockIdx.x * blockDim.x + threadIdx.x;
  if (i >= K * NN) return;
  int n = i / K, k = i - n * K;
  WT[i] = f2bf(W[(size_t)k * NN + n]);
}

// ---------------- bf16 MFMA GEMM: C[M][NN] = A[M][K] * BT[NN][K]^T ----------------
// 128x128 tile, 4 waves (2x2), each wave 64x64 via 4x4 frags of 16x16x32.

#define LDSPAD 40  // bf16 elements per LDS row (80 B = 5x16B, conflict-light)

template<typename CT>
__global__ __launch_bounds__(256) void k_mm(const u16* __restrict__ A, const u16* __restrict__ BT,
                                            CT* __restrict__ C, int M, int NN, int K) {
  __shared__ u16 As[128 * LDSPAD];
  __shared__ u16 Bs[128 * LDSPAD];
  const int tid = threadIdx.x;
  const int wid = tid >> 6, lane = tid & 63;
  const int wr = wid >> 1, wc = wid & 1;
  const int m0 = blockIdx.x * 128, n0 = blockIdx.y * 128;
  f32x4 acc[4][4] = {};
  const int tr = tid >> 2, tc = (tid & 3) * 8;  // staging: row, col-chunk (8 bf16 = 16 B)
  const int fr = lane & 15, fk = (lane >> 4) * 8;
  for (int k0 = 0; k0 < K; k0 += 32) {
    #pragma unroll
    for (int half = 0; half < 2; ++half) {
      const int r = tr + half * 64;
      uint4 va = {0, 0, 0, 0};
      const int gm = m0 + r;
      if (gm < M) va = *(const uint4*)(A + (size_t)gm * K + k0 + tc);
      *(uint4*)(&As[r * LDSPAD + tc]) = va;
      const uint4 vb = *(const uint4*)(BT + (size_t)(n0 + r) * K + k0 + tc);
      *(uint4*)(&Bs[r * LDSPAD + tc]) = vb;
    }
    __syncthreads();
    bf16x8 af[4], bf[4];
    #pragma unroll
    for (int m = 0; m < 4; ++m) af[m] = *(const bf16x8*)(&As[(wr * 64 + m * 16 + fr) * LDSPAD + fk]);
    #pragma unroll
    for (int n = 0; n < 4; ++n) bf[n] = *(const bf16x8*)(&Bs[(wc * 64 + n * 16 + fr) * LDSPAD + fk]);
    #pragma unroll
    for (int m = 0; m < 4; ++m)
      #pragma unroll
      for (int n = 0; n < 4; ++n)
        acc[m][n] = __builtin_amdgcn_mfma_f32_16x16x32_bf16(af[m], bf[n], acc[m][n], 0, 0, 0);
    __syncthreads();
  }
  const int col = lane & 15, rbase = (lane >> 4) * 4;
  #pragma unroll
  for (int m = 0; m < 4; ++m)
    #pragma unroll
    for (int n = 0; n < 4; ++n)
      #pragma unroll
      for (int q = 0; q < 4; ++q) {
        const int gm = m0 + wr * 64 + m * 16 + rbase + q;
        const int gn = n0 + wc * 64 + n * 16 + col;
        if (gm < M) {
          float v = acc[m][n][q];
          if constexpr (sizeof(CT) == 2) C[(size_t)gm * NN + gn] = (CT)f2bf(v);
          else                           C[(size_t)gm * NN + gn] = (CT)v;
        }
      }
}

// ---------------- attention coefficients ----------------

__global__ __launch_bounds__(256) void k_alpha1(const u16* __restrict__ xh,
                                                const float* __restrict__ a_src,
                                                const float* __restrict__ a_dst,
                                                float* __restrict__ as_out,
                                                float* __restrict__ ad_out, int N) {
  int g = blockIdx.x * 4 + (threadIdx.x >> 6);
  int lane = threadIdx.x & 63;
  if (g >= N) return;
  const u32* urow = (const u32*)(xh + (size_t)g * 512);
  float sv[4], dv[4];
  #pragma unroll
  for (int h = 0; h < 4; ++h) {
    u32 w = urow[h * 64 + lane];
    float x0 = bf2f(w & 0xffffu), x1 = __uint_as_float(w & 0xffff0000u);
    int c = h * 128 + 2 * lane;
    sv[h] = x0 * a_src[c] + x1 * a_src[c + 1];
    dv[h] = x0 * a_dst[c] + x1 * a_dst[c + 1];
  }
  #pragma unroll
  for (int s = 32; s; s >>= 1) {
    #pragma unroll
    for (int h = 0; h < 4; ++h) {
      sv[h] += __shfl_xor(sv[h], s);
      dv[h] += __shfl_xor(dv[h], s);
    }
  }
  if (lane == 0) {
    #pragma unroll
    for (int h = 0; h < 4; ++h) {
      as_out[g * 4 + h] = sv[h];
      ad_out[g * 4 + h] = dv[h];
    }
  }
}

__global__ __launch_bounds__(256) void k_alpha2(const u16* __restrict__ xh,
                                                const float* __restrict__ a_src,
                                                const float* __restrict__ a_dst,
                                                float* __restrict__ as_out,
                                                float* __restrict__ ad_out, int N) {
  int g = blockIdx.x * 4 + (threadIdx.x >> 6);
  int lane = threadIdx.x & 63;
  if (g >= N) return;
  u32 w = *(const u32*)(xh + (size_t)g * 128 + lane * 2);
  float x0 = bf2f(w & 0xffffu), x1 = __uint_as_float(w & 0xffff0000u);
  float vs = x0 * a_src[2 * lane] + x1 * a_src[2 * lane + 1];
  float vd = x0 * a_dst[2 * lane] + x1 * a_dst[2 * lane + 1];
  #pragma unroll
  for (int s = 32; s; s >>= 1) {
    vs += __shfl_xor(vs, s);
    vd += __shfl_xor(vd, s);
  }
  if (lane == 0) { as_out[g] = vs; ad_out[g] = vd; }
}

// ---------------- GAT aggregation (wave per node) ----------------

#define CAP1 128
__global__ __launch_bounds__(256) void k_agg1(
    const u16* __restrict__ xh, const float* __restrict__ as_, const float* __restrict__ ad_,
    const int* __restrict__ csr, const int* __restrict__ rowp, const int* __restrict__ cnt,
    const float* __restrict__ bias, u16* __restrict__ hout, int N) {
  __shared__ int s_src[4][CAP1];
  __shared__ float s_ex[4][CAP1][4];
  const int wv = threadIdx.x >> 6, lane = threadIdx.x & 63;
  const int dn = blockIdx.x * 4 + wv;
  if (dn >= N) return;
  const int start = rowp[dn], deg = cnt[dn] + 1;
  const float4 ad4 = *(const float4*)(ad_ + (size_t)dn * 4);
  float m0 = -1e30f, m1 = -1e30f, m2 = -1e30f, m3 = -1e30f;
  for (int i = lane; i < deg; i += 64) {
    const float4 a4 = *(const float4*)(as_ + (size_t)csr[start + i] * 4);
    float e;
    e = a4.x + ad4.x; e = e > 0.f ? e : 0.2f * e; m0 = fmaxf(m0, e);
    e = a4.y + ad4.y; e = e > 0.f ? e : 0.2f * e; m1 = fmaxf(m1, e);
    e = a4.z + ad4.z; e = e > 0.f ? e : 0.2f * e; m2 = fmaxf(m2, e);
    e = a4.w + ad4.w; e = e > 0.f ? e : 0.2f * e; m3 = fmaxf(m3, e);
  }
  #pragma unroll
  for (int s = 32; s; s >>= 1) {
    m0 = fmaxf(m0, __shfl_xor(m0, s));
    m1 = fmaxf(m1, __shfl_xor(m1, s));
    m2 = fmaxf(m2, __shfl_xor(m2, s));
    m3 = fmaxf(m3, __shfl_xor(m3, s));
  }
  const int hj = lane >> 4;  // head owned by this lane's 8 channels
  float d0 = 0.f, d1 = 0.f, d2 = 0.f, d3 = 0.f;
  float acc[8] = {};
  for (int c0 = 0; c0 < deg; c0 += CAP1) {
    const int cn = min(CAP1, deg - c0);
    for (int i = lane; i < cn; i += 64) {
      const int s = csr[start + c0 + i];
      s_src[wv][i] = s;
      const float4 a4 = *(const float4*)(as_ + (size_t)s * 4);
      float e, ex;
      e = a4.x + ad4.x; e = e > 0.f ? e : 0.2f * e; ex = __expf(e - m0); s_ex[wv][i][0] = ex; d0 += ex;
      e = a4.y + ad4.y; e = e > 0.f ? e : 0.2f * e; ex = __expf(e - m1); s_ex[wv][i][1] = ex; d1 += ex;
      e = a4.z + ad4.z; e = e > 0.f ? e : 0.2f * e; ex = __expf(e - m2); s_ex[wv][i][2] = ex; d2 += ex;
      e = a4.w + ad4.w; e = e > 0.f ? e : 0.2f * e; ex = __expf(e - m3); s_ex[wv][i][3] = ex; d3 += ex;
    }
    for (int i = 0; i < cn; ++i) {
      const uint4 v = *(const uint4*)(xh + (size_t)s_src[wv][i] * 512 + lane * 8);
      const float ex = s_ex[wv][i][hj];
      acc[0] = fmaf(ex, bf2f(v.x & 0xffffu), acc[0]);
      acc[1] = fmaf(ex, __uint_as_float(v.x & 0xffff0000u), acc[1]);
      acc[2] = fmaf(ex, bf2f(v.y & 0xffffu), acc[2]);
      acc[3] = fmaf(ex, __uint_as_float(v.y & 0xffff0000u), acc[3]);
      acc[4] = fmaf(ex, bf2f(v.z & 0xffffu), acc[4]);
      acc[5] = fmaf(ex, __uint_as_float(v.z & 0xffff0000u), acc[5]);
      acc[6] = fmaf(ex, bf2f(v.w & 0xffffu), acc[6]);
      acc[7] = fmaf(ex, __uint_as_float(v.w & 0xffff0000u), acc[7]);
    }
  }
  #pragma unroll
  for (int s = 32; s; s >>= 1) {
    d0 += __shfl_xor(d0, s); d1 += __shfl_xor(d1, s);
    d2 += __shfl_xor(d2, s); d3 += __shfl_xor(d3, s);
  }
  const float denom = (hj == 0) ? d0 : (hj == 1) ? d1 : (hj == 2) ? d2 : d3;
  const float inv = 1.f / denom;
  const int c0 = lane * 8;
  u32 ow[4];
  #pragma unroll
  for (int p = 0; p < 4; ++p) {
    float v0 = acc[2 * p] * inv + bias[c0 + 2 * p];
    float v1 = acc[2 * p + 1] * inv + bias[c0 + 2 * p + 1];
    v0 = v0 > 0.f ? v0 : __expf(v0) - 1.f;  // ELU fused
    v1 = v1 > 0.f ? v1 : __expf(v1) - 1.f;
    ow[p] = (u32)f2bf(v0) | ((u32)f2bf(v1) << 16);
  }
  uint4 o; o.x = ow[0]; o.y = ow[1]; o.z = ow[2]; o.w = ow[3];
  *(uint4*)(hout + (size_t)dn * 512 + lane * 8) = o;
}

#define CAP2 128
__global__ __launch_bounds__(256) void k_agg2(
    const u16* __restrict__ xh, const float* __restrict__ as_, const float* __restrict__ ad_,
    const int* __restrict__ csr, const int* __restrict__ rowp, const int* __restrict__ cnt,
    const float* __restrict__ bias, float* __restrict__ hout, int N) {
  __shared__ int s_src[4][CAP2];
  __shared__ float s_ex[4][CAP2];
  const int wv = threadIdx.x >> 6, lane = threadIdx.x & 63;
  const int dn = blockIdx.x * 4 + wv;
  if (dn >= N) return;
  const int start = rowp[dn], deg = cnt[dn] + 1;
  const float adv = ad_[dn];
  float mx = -1e30f;
  for (int i = lane; i < deg; i += 64) {
    float e = as_[csr[start + i]] + adv;
    e = e > 0.f ? e : 0.2f * e;
    mx = fmaxf(mx, e);
  }
  #pragma unroll
  for (int s = 32; s; s >>= 1) mx = fmaxf(mx, __shfl_xor(mx, s));
  float dsum = 0.f, acc0 = 0.f, acc1 = 0.f;
  for (int c0 = 0; c0 < deg; c0 += CAP2) {
    const int cn = min(CAP2, deg - c0);
    for (int i = lane; i < cn; i += 64) {
      const int s = csr[start + c0 + i];
      s_src[wv][i] = s;
      float e = as_[s] + adv;
      e = e > 0.f ? e : 0.2f * e;
      float ex = __expf(e - mx);
      s_ex[wv][i] = ex;
      dsum += ex;
    }
    for (int i = 0; i < cn; ++i) {
      const u32 w = *(const u32*)(xh + (size_t)s_src[wv][i] * 128 + lane * 2);
      const float ex = s_ex[wv][i];
      acc0 = fmaf(ex, bf2f(w & 0xffffu), acc0);
      acc1 = fmaf(ex, __uint_as_float(w & 0xffff0000u), acc1);
    }
  }
  #pragma unroll
  for (int s = 32; s; s >>= 1) dsum += __shfl_xor(dsum, s);
  const float inv = 1.f / dsum;
  float2 o;
  o.x = acc0 * inv + bias[2 * lane];
  o.y = acc1 * inv + bias[2 * lane + 1];
  *(float2*)(hout + (size_t)dn * 128 + lane * 2) = o;
}

// ---------------- final regression head ----------------
__global__ __launch_bounds__(256) void k_head(const float* __restrict__ h2,
                                              const float* __restrict__ fcw,
                                              const float* __restrict__ fcb,
                                              float* __restrict__ out, int N) {
  int g = blockIdx.x * 4 + (threadIdx.x >> 6);
  int lane = threadIdx.x & 63;
  if (g >= N) return;
  const float* r = h2 + (size_t)g * 128;
  float acc = r[lane] * fcw[lane] + r[64 + lane] * fcw[64 + lane];
  #pragma unroll
  for (int s = 32; s; s >>= 1) acc += __shfl_xor(acc, s);
  if (lane == 0) out[g] = acc + fcb[0];
}

// ---------------- launch ----------------
extern "C" void kernel_launch(void* const* d_in, const int* in_sizes, int n_in,
                              void* d_out, int out_size, void* d_ws, size_t ws_size,
                              hipStream_t stream) {
  const float* x      = (const float*)d_in[0];
  const void*  ei     = d_in[1];
  const float* W1     = (const float*)d_in[2];
  const float* a_src1 = (const float*)d_in[3];
  const float* a_dst1 = (const float*)d_in[4];
  const float* b1     = (const float*)d_in[5];
  const float* W2     = (const float*)d_in[6];
  const float* a_src2 = (const float*)d_in[7];
  const float* a_dst2 = (const float*)d_in[8];
  const float* b2     = (const float*)d_in[9];
  const float* fc_w   = (const float*)d_in[10];
  const float* fc_b   = (const float*)d_in[11];
  const int N = in_sizes[0] / IN_DIM;
  const int E = in_sizes[1] / 2;

  char* w = (char*)d_ws;
  size_t off = 0;
  auto take = [&](size_t bytes) -> char* {
    char* p = w + off;
    off += (bytes + 255) & ~(size_t)255;
    return p;
  };
  int*   hdr    = (int*)take(256);                 // [0]=eflag, [1]=total
  int*   src32  = (int*)take((size_t)E * 4);
  int*   dst32  = (int*)take((size_t)E * 4);
  int*   cnt    = (int*)take((size_t)N * 4);
  int*   rowp   = (int*)take((size_t)N * 4);
  int*   cursor = (int*)take((size_t)N * 4);
  int*   csr    = (int*)take((size_t)(E + N) * 4);
  float* as1    = (float*)take((size_t)N * 16);
  float* ad1    = (float*)take((size_t)N * 16);
  float* as2    = (float*)take((size_t)N * 4);
  float* ad2    = (float*)take((size_t)N * 4);
  u16*   xbf    = (u16*)take((size_t)N * 128 * 2);
  u16*   wt1    = (u16*)take((size_t)512 * 128 * 2);
  u16*   wt2    = (u16*)take((size_t)128 * 512 * 2);
  u16*   xh1    = (u16*)take((size_t)N * 512 * 2);
  u16*   h1     = (u16*)take((size_t)N * 512 * 2);
  u16*   xh2    = (u16*)take((size_t)N * 128 * 2);
  float* h2     = (float*)take((size_t)N * 128 * 4);
  (void)ws_size; (void)n_in; (void)out_size;

  hipMemsetAsync(hdr, 0, 256, stream);
  hipMemsetAsync(cnt, 0, (size_t)N * 4, stream);

  k_detect<<<1, 64, 0, stream>>>((const u32*)ei, hdr, E);
  const int gE = (E + 255) / 256;
  k_convert<<<gE, 256, 0, stream>>>(ei, src32, dst32, E, hdr);
  k_count<<<gE, 256, 0, stream>>>(dst32, cnt, E);
  k_alloc<<<(N + 255) / 256, 256, 0, stream>>>(cnt, rowp, cursor, hdr + 1, N);
  k_scatter<<<(E + N + 255) / 256, 256, 0, stream>>>(src32, dst32, cursor, csr, E, N);

  k_castbf<<<(N * 128 / 4 + 255) / 256, 256, 0, stream>>>(x, xbf, N * 128 / 4);
  k_transW<<<(512 * 128 + 255) / 256, 256, 0, stream>>>(W1, wt1, 128, 512);
  k_transW<<<(512 * 128 + 255) / 256, 256, 0, stream>>>(W2, wt2, 512, 128);

  const int mt = (N + 127) / 128;
  k_mm<u16><<<dim3(mt, 4), 256, 0, stream>>>(xbf, wt1, xh1, N, 512, 128);
  k_alpha1<<<(N + 3) / 4, 256, 0, stream>>>(xh1, a_src1, a_dst1, as1, ad1, N);
  k_agg1<<<(N + 3) / 4, 256, 0, stream>>>(xh1, as1, ad1, csr, rowp, cnt, b1, h1, N);

  k_mm<u16><<<dim3(mt, 1), 256, 0, stream>>>(h1, wt2, xh2, N, 128, 512);
  k_alpha2<<<(N + 3) / 4, 256, 0, stream>>>(xh2, a_src2, a_dst2, as2, ad2, N);
  k_agg2<<<(N + 3) / 4, 256, 0, stream>>>(xh2, as2, ad2, csr, rowp, cnt, b2, h2, N);

  k_head<<<(N + 3) / 4, 256, 0, stream>>>(h2, fc_w, fc_b, (float*)d_out, N);
}